// Round 11
// baseline (366.612 us; speedup 1.0000x reference)
//
#include <hip/hip_runtime.h>
#include <hip/hip_bf16.h>

// Problem constants
#define C_   32
#define S_   20
#define V_   8000     // 20^3
#define K3_  125
#define KP_  128      // K3 padded (taps 125..127 have zero B)
#define OC_  375      // 3*K3
#define NP_  384      // padded N
#define KK_  4000     // 32*125
#define PS   24       // padded spatial
#define PS2  576
#define PV   13824    // 24^3

// Workspace layout (float offsets). Peak 2.816M floats = 11.26 MB.
#define WS_ATTN1T 0                        // fp32 [v][c]           256000
#define WS_XPAD   256000                   // bf16 [24][24][24][32] 221184 fl
#define WS_WDWT   477184                   // fp32 [k][c]             4000
#define WS_WSPT   481184                   // fp32 [k][c]            10976
#define WS_WPWT   492160                   // fp32 [c][o]             1024
#define WS_OFFB   493184                   // bf16 [v][384]        1536000 fl
#define WS_B2     2029184                  // bf16 [128][384][32]   786432 fl

typedef __attribute__((ext_vector_type(8))) short bf16x8;
typedef __attribute__((ext_vector_type(4))) float f32x4;

static __device__ __forceinline__ unsigned short f2bf(float f) {
    union { float f; unsigned u; } v; v.f = f;
    unsigned r = v.u + 0x7FFFu + ((v.u >> 16) & 1u);   // RTNE
    return (unsigned short)(r >> 16);
}
static __device__ __forceinline__ float bf2f(unsigned short b) {
    union { unsigned u; float f; } v; v.u = ((unsigned)b) << 16; return v.f;
}
static __device__ __forceinline__ float asf(unsigned u) {
    union { unsigned u; float f; } v; v.u = u; return v.f;
}

// ---------------------------------------------------------------------------
// Prep (fused): xpad[pz][py][px][c] bf16 zero-padded; wdwT/wspT/wpwT fp32
// transposes; B2[tap][n][c] bf16 (tap>=125 or n>=375 zeroed).
// ---------------------------------------------------------------------------
__global__ __launch_bounds__(256) void prep_kernel(
    const float* __restrict__ x,
    const float* __restrict__ w_off,
    const float* __restrict__ w_dw,
    const float* __restrict__ w_sp,
    const float* __restrict__ w_pw,
    unsigned short* __restrict__ xpad,
    float* __restrict__ wdwT,
    float* __restrict__ wspT,
    float* __restrict__ wpwT,
    unsigned short* __restrict__ B2)
{
    int i = blockIdx.x * 256 + threadIdx.x;
    if (i < PV * C_) {
        int vp = i >> 5, c = i & 31;
        int pz = vp / PS2, rm = vp % PS2;
        int py = rm / PS, px = rm % PS;
        int z = pz - 2, y = py - 2, xx = px - 2;
        unsigned short val = 0;
        if ((unsigned)z < (unsigned)S_ && (unsigned)y < (unsigned)S_ &&
            (unsigned)xx < (unsigned)S_)
            val = f2bf(x[c * V_ + z * 400 + y * 20 + xx]);
        xpad[i] = val;
        return;
    }
    int j = i - PV * C_;
    if (j < 4000)  { wdwT[j] = w_dw[(j & 31) * K3_ + (j >> 5)]; return; }
    j -= 4000;
    if (j < 10976) { wspT[j] = w_sp[(j & 31) * 343 + (j >> 5)]; return; }
    j -= 10976;
    if (j < 1024)  { wpwT[j] = w_pw[(j & 31) * 32 + (j >> 5)]; return; }
    j -= 1024;
    if (j < KP_ * NP_ * C_) {
        int tap = j / 12288, r = j % 12288;
        int n = r >> 5, c = r & 31;
        float v = (n < OC_ && tap < K3_) ? w_off[n * KK_ + c * K3_ + tap] : 0.f;
        B2[j] = f2bf(v);
    }
}

// ---------------------------------------------------------------------------
// Offset conv as implicit-GEMM MFMA: D[8000][384] = A[8000][4000]*B[4000][384].
// LDS-staged (r6 structure) with three fixes:
//  - XOR swizzle on the SOURCE address (srcq = (l&3)^((l>>3)&3)); LDS writes
//    stay lane-contiguous (conflict-free), frag ds_read_b128 lands 2-way max.
//  - BK=128 (4 taps/stage): 16 MFMA per barrier pair, 32 stages (K padded,
//    zero-B tail).
//  - Register double-buffer: next stage's 8 global loads issue right after
//    the ds_write barrier; latency hides under the 4-tap compute.
// Tile 64x64, waves 2x2, wave tile 32x32, mfma 16x16x32 bf16, grid (125,6).
// ---------------------------------------------------------------------------
__global__ __launch_bounds__(256) void gemm_off_kernel(
    const unsigned short* __restrict__ xpad,
    const unsigned short* __restrict__ B2,
    const float* __restrict__ b_off,
    unsigned short* __restrict__ offbT)
{
    __shared__ unsigned short Alds[4 * 64 * 32];   // 16 KB
    __shared__ unsigned short Blds[4 * 64 * 32];   // 16 KB

    const int t    = threadIdx.x;
    const int l    = t & 63;
    const int w    = t >> 6;
    const int wr   = w >> 1;
    const int wc   = w & 1;
    const int quad = l >> 4;
    const int lrow = l & 15;
    const int M0   = blockIdx.x * 64;
    const int N0   = blockIdx.y * 64;

    // Staging: wave w handles tap (st*4+w); instr i covers rows i*16..i*16+15.
    // Source-address swizzle (content goes to LDS col l&3, holds channels srcq*8).
    const int srcq = (l & 3) ^ ((l >> 3) & 3);
    const unsigned short* asrc[4];
    const unsigned short* bsrc[4];
    #pragma unroll
    for (int i = 0; i < 4; ++i) {
        int r = i * 16 + (l >> 2);
        int m = M0 + r;                            // < 8000 always (125*64)
        int az = m / 400, rr = m % 400, ay = rr / 20, ax = rr % 20;
        asrc[i] = xpad + (az * PS2 + ay * PS + ax) * 32 + srcq * 8;
        bsrc[i] = B2 + (size_t)(N0 + r) * 32 + srcq * 8;
    }
    uint4* adst = (uint4*)&Alds[w * 2048];
    uint4* bdst = (uint4*)&Blds[w * 2048];

    // Frag-read swizzle: col read = quad ^ ((row>>1)&3) = quad ^ ((lrow>>1)&3).
    const int qr = quad ^ ((lrow >> 1) & 3);

    uint4 pa[4], pb[4];
    auto fetch = [&](int st) {
        int tap = st * 4 + w;
        int tc = min(tap, K3_ - 1);
        int kz = tc / 25, r5 = tc % 25, ky = r5 / 5, kx = r5 % 5;
        int toff = (kz * PS2 + ky * PS + kx) * 32;   // wave-uniform
        #pragma unroll
        for (int i = 0; i < 4; ++i) {
            pa[i] = *(const uint4*)(asrc[i] + toff);
            pb[i] = *(const uint4*)(bsrc[i] + (size_t)tap * 12288);
        }
    };

    fetch(0);
    f32x4 acc[2][2] = {};

    #pragma unroll 1
    for (int st = 0; st < 32; ++st) {
        __syncthreads();                 // previous stage's LDS reads done
        #pragma unroll
        for (int i = 0; i < 4; ++i) {
            adst[i * 64 + l] = pa[i];
            bdst[i * 64 + l] = pb[i];
        }
        __syncthreads();                 // staging visible
        if (st < 31) fetch(st + 1);      // overlap next loads with compute
        #pragma unroll
        for (int s = 0; s < 4; ++s) {
            bf16x8 af[2], bf[2];
            #pragma unroll
            for (int mi = 0; mi < 2; ++mi)
                af[mi] = *(const bf16x8*)&Alds[s * 2048 + (wr * 32 + mi * 16 + lrow) * 32 + qr * 8];
            #pragma unroll
            for (int ni = 0; ni < 2; ++ni)
                bf[ni] = *(const bf16x8*)&Blds[s * 2048 + (wc * 32 + ni * 16 + lrow) * 32 + qr * 8];
            #pragma unroll
            for (int mi = 0; mi < 2; ++mi)
                #pragma unroll
                for (int ni = 0; ni < 2; ++ni)
                    acc[mi][ni] = __builtin_amdgcn_mfma_f32_16x16x32_bf16(
                        af[mi], bf[ni], acc[mi][ni], 0, 0, 0);
        }
    }

    #pragma unroll
    for (int mi = 0; mi < 2; ++mi) {
        #pragma unroll
        for (int ni = 0; ni < 2; ++ni) {
            int n = N0 + wc * 32 + ni * 16 + lrow;
            if (n < OC_) {
                float bias = b_off[n];
                #pragma unroll
                for (int r = 0; r < 4; ++r) {
                    int row = wr * 32 + mi * 16 + quad * 4 + r;
                    offbT[(size_t)(M0 + row) * 384 + n] = f2bf(acc[mi][ni][r] + bias);
                }
            }
        }
    }
}

// ---------------------------------------------------------------------------
// Deformable depthwise sample, two-phase (gathers from padded volume).
// Phase 1: per (voxel, tap) geometry computed ONCE -> 24B in LDS.
// Phase 2: thread=(v,c); 3 broadcast LDS dwords + 8 coalesced gathers + FMAs.
// ---------------------------------------------------------------------------
#define VB 8
__global__ __launch_bounds__(256) void deform_kernel(
    const unsigned short* __restrict__ xpad,
    const float* __restrict__ wdwT,
    const float* __restrict__ b_dw,
    const unsigned short* __restrict__ offbT,
    float* __restrict__ attn1T)
{
    __shared__ unsigned short sw[VB * 128 * 12];   // 24 KB
    const int tid = threadIdx.x;
    const int Vb = blockIdx.x * VB;

    for (int idx = tid; idx < VB * 128; idx += 256) {
        int vl = idx >> 7, tap = idx & 127;
        if (tap < K3_) {
            int v = Vb + vl;
            int z = v / 400, rm = v % 400;
            int y = rm / 20, xx = rm % 20;
            int kz = tap / 25, ky = (tap / 5) % 5, kx = tap % 5;
            const unsigned short* ob = offbT + v * 384 + 3 * tap;
            float pd = (float)(z - 2 + kz) + bf2f(ob[0]);
            float ph = (float)(y - 2 + ky) + bf2f(ob[1]);
            float pw = (float)(xx - 2 + kx) + bf2f(ob[2]);
            float fd0 = floorf(pd), fh0 = floorf(ph), fw0 = floorf(pw);
            float fd = pd - fd0, fh = ph - fh0, fw = pw - fw0;
            int id = (int)fd0, ih = (int)fh0, iw = (int)fw0;
            int d0 = min(max(id, 0), S_ - 1), d1 = min(max(id + 1, 0), S_ - 1);
            int h0 = min(max(ih, 0), S_ - 1), h1 = min(max(ih + 1, 0), S_ - 1);
            int w0 = min(max(iw, 0), S_ - 1), w1 = min(max(iw + 1, 0), S_ - 1);
            float wd0 = ((unsigned)id       < (unsigned)S_) ? 1.f - fd : 0.f;
            float wd1 = ((unsigned)(id + 1) < (unsigned)S_) ? fd       : 0.f;
            float wh0 = ((unsigned)ih       < (unsigned)S_) ? 1.f - fh : 0.f;
            float wh1 = ((unsigned)(ih + 1) < (unsigned)S_) ? fh       : 0.f;
            float ww0 = ((unsigned)iw       < (unsigned)S_) ? 1.f - fw : 0.f;
            float ww1 = ((unsigned)(iw + 1) < (unsigned)S_) ? fw       : 0.f;
            unsigned short* p = &sw[idx * 12];
            p[0] = f2bf(wd0 * wh0); p[1] = f2bf(wd0 * wh1);
            p[2] = f2bf(wd1 * wh0); p[3] = f2bf(wd1 * wh1);
            p[4] = f2bf(ww0);       p[5] = f2bf(ww1);
            p[6] = (unsigned short)((d0 + 2) * PS2 + (h0 + 2) * PS + 2);
            p[7] = (unsigned short)((d0 + 2) * PS2 + (h1 + 2) * PS + 2);
            p[8] = (unsigned short)((d1 + 2) * PS2 + (h0 + 2) * PS + 2);
            p[9] = (unsigned short)((d1 + 2) * PS2 + (h1 + 2) * PS + 2);
            p[10] = (unsigned short)w0; p[11] = (unsigned short)w1;
        }
    }
    __syncthreads();

    const int c = tid & 31;
    const int vl = tid >> 5;
    const int v = Vb + vl;
    const unsigned short* xc = xpad + c;
    float acc = 0.f;
    #pragma unroll 2
    for (int tap = 0; tap < K3_; ++tap) {
        const unsigned* pu = (const unsigned*)&sw[(vl * 128 + tap) * 12];
        unsigned u0 = pu[0], u1 = pu[1], u2 = pu[2];
        unsigned u3 = pu[3], u4 = pu[4], u5 = pu[5];
        float wdh00 = asf(u0 << 16), wdh01 = asf(u0 & 0xFFFF0000u);
        float wdh10 = asf(u1 << 16), wdh11 = asf(u1 & 0xFFFF0000u);
        float ww0   = asf(u2 << 16), ww1   = asf(u2 & 0xFFFF0000u);
        int r00 = u3 & 0xFFFFu, r01 = u3 >> 16;
        int r10 = u4 & 0xFFFFu, r11 = u4 >> 16;
        int w0  = u5 & 0xFFFFu, w1  = u5 >> 16;
        float x000 = bf2f(xc[(r00 + w0) * 32]);
        float x001 = bf2f(xc[(r00 + w1) * 32]);
        float x010 = bf2f(xc[(r01 + w0) * 32]);
        float x011 = bf2f(xc[(r01 + w1) * 32]);
        float x100 = bf2f(xc[(r10 + w0) * 32]);
        float x101 = bf2f(xc[(r10 + w1) * 32]);
        float x110 = bf2f(xc[(r11 + w0) * 32]);
        float x111 = bf2f(xc[(r11 + w1) * 32]);
        float s = (x000 * ww0 + x001 * ww1) * wdh00
                + (x010 * ww0 + x011 * ww1) * wdh01
                + (x100 * ww0 + x101 * ww1) * wdh10
                + (x110 * ww0 + x111 * ww1) * wdh11;
        acc += wdwT[tap * 32 + c] * s;
    }
    attn1T[v * 32 + c] = acc + b_dw[c];
}

// ---------------------------------------------------------------------------
// Fused: depthwise 7^3 dil-3 conv + pointwise 32x32 + bias + gate.
// Block = 8 voxels x 32 channels; attn2 handed through LDS (never hits HBM).
// ---------------------------------------------------------------------------
__global__ __launch_bounds__(256) void spatial_pw_kernel(
    const float* __restrict__ wspT,
    const float* __restrict__ b_sp,
    const float* __restrict__ wpwT,
    const float* __restrict__ b_pw,
    const float* __restrict__ x,
    const float* __restrict__ attn1T,
    float* __restrict__ out)
{
    __shared__ float s2[8][32];
    int t = threadIdx.x;
    int c = t & 31;
    int vl = t >> 5;
    int v = blockIdx.x * 8 + vl;
    int z = v / 400, rm = v % 400;
    int y = rm / 20, xx = rm % 20;

    float acc = 0.f;
    #pragma unroll 1
    for (int kz = 0; kz < 7; ++kz) {
        int zi = z - 9 + 3 * kz;
        bool zv = (unsigned)zi < (unsigned)S_;
        int zc2 = min(max(zi, 0), S_ - 1);
        #pragma unroll 1
        for (int ky = 0; ky < 7; ++ky) {
            int yi = y - 9 + 3 * ky;
            bool yv = (unsigned)yi < (unsigned)S_;
            int yc2 = min(max(yi, 0), S_ - 1);
            int abase = (zc2 * 400 + yc2 * 20) * 32 + c;
            int wbase = (kz * 49 + ky * 7) * 32 + c;
            #pragma unroll
            for (int kx = 0; kx < 7; ++kx) {
                int xi = xx - 9 + 3 * kx;
                bool xv = (unsigned)xi < (unsigned)S_;
                int xc2 = min(max(xi, 0), S_ - 1);
                float a = attn1T[abase + xc2 * 32];
                float w = wspT[wbase + kx * 32];
                acc += (zv && yv && xv) ? a * w : 0.f;
            }
        }
    }
    s2[vl][c] = acc + b_sp[c];
    __syncthreads();

    int o = c;   // reuse lane as output channel
    float r = b_pw[o];
    #pragma unroll
    for (int cc = 0; cc < C_; ++cc)
        r += wpwT[cc * 32 + o] * s2[vl][cc];
    out[o * V_ + v] = x[o * V_ + v] * r;
}

// ---------------------------------------------------------------------------
extern "C" void kernel_launch(void* const* d_in, const int* in_sizes, int n_in,
                              void* d_out, int out_size, void* d_ws, size_t ws_size,
                              hipStream_t stream)
{
    const float* x     = (const float*)d_in[0];
    const float* w_off = (const float*)d_in[1];
    const float* b_off = (const float*)d_in[2];
    const float* w_dw  = (const float*)d_in[3];
    const float* b_dw  = (const float*)d_in[4];
    const float* w_sp  = (const float*)d_in[5];
    const float* b_sp  = (const float*)d_in[6];
    const float* w_pw  = (const float*)d_in[7];
    const float* b_pw  = (const float*)d_in[8];
    float* ws = (float*)d_ws;
    float* out = (float*)d_out;

    unsigned short* xpad  = (unsigned short*)(ws + WS_XPAD);
    unsigned short* offbT = (unsigned short*)(ws + WS_OFFB);
    unsigned short* B2    = (unsigned short*)(ws + WS_B2);

    const int n_prep = PV * C_ + 16000 + KP_ * NP_ * C_;
    hipLaunchKernelGGL(prep_kernel, dim3((n_prep + 255) / 256), dim3(256), 0, stream,
                       x, w_off, w_dw, w_sp, w_pw, xpad,
                       ws + WS_WDWT, ws + WS_WSPT, ws + WS_WPWT, B2);

    hipLaunchKernelGGL(gemm_off_kernel, dim3(125, 6), dim3(256), 0, stream,
                       xpad, B2, b_off, offbT);

    hipLaunchKernelGGL(deform_kernel, dim3(1000), dim3(256), 0, stream,
                       xpad, ws + WS_WDWT, b_dw, offbT, ws + WS_ATTN1T);

    hipLaunchKernelGGL(spatial_pw_kernel, dim3(1000), dim3(256), 0, stream,
                       ws + WS_WSPT, b_sp, ws + WS_WPWT, b_pw, x,
                       ws + WS_ATTN1T, out);
}